// Round 1
// baseline (604.439 us; speedup 1.0000x reference)
//
#include <hip/hip_runtime.h>

#define BB 8
#define NN 1024
#define DM 256
#define HH 8
#define HD 32
#define TC 768   // 3*DM

// ---------------- QKV projection GEMM ----------------
// x[B*N, DM] @ W[DM, TC] + bias -> Q,K,V each [B,H,N,HD] in workspace
__global__ __launch_bounds__(256) void qkv_kernel(
    const float* __restrict__ x, const float* __restrict__ W,
    const float* __restrict__ bias, float* __restrict__ Qo,
    float* __restrict__ Ko, float* __restrict__ Vo)
{
  __shared__ float As[16][68];  // [k][m] transposed
  __shared__ float Bs[16][68];  // [k][c]
  const int tid = threadIdx.x;
  const int m0 = blockIdx.y * 64;
  const int c0 = blockIdx.x * 64;
  const int ty = tid >> 4, tx = tid & 15;
  float acc[4][4] = {};
  for (int k0 = 0; k0 < DM; k0 += 16) {
    {
      int row = tid >> 2, kq = tid & 3;
      const float4 v = *(const float4*)&x[(size_t)(m0 + row) * DM + k0 + kq * 4];
      As[kq*4+0][row] = v.x; As[kq*4+1][row] = v.y;
      As[kq*4+2][row] = v.z; As[kq*4+3][row] = v.w;
    }
    {
      int k = tid >> 4, cq = tid & 15;
      *(float4*)&Bs[k][cq*4] = *(const float4*)&W[(size_t)(k0 + k) * TC + c0 + cq * 4];
    }
    __syncthreads();
    #pragma unroll
    for (int kk = 0; kk < 16; ++kk) {
      float4 a4 = *(const float4*)&As[kk][ty*4];
      float4 b4 = *(const float4*)&Bs[kk][tx*4];
      float a[4] = {a4.x, a4.y, a4.z, a4.w};
      float b[4] = {b4.x, b4.y, b4.z, b4.w};
      #pragma unroll
      for (int i = 0; i < 4; ++i)
        #pragma unroll
        for (int j = 0; j < 4; ++j)
          acc[i][j] += a[i] * b[j];
    }
    __syncthreads();
  }
  #pragma unroll
  for (int i = 0; i < 4; ++i) {
    int m = m0 + ty*4 + i;
    int bb = m >> 10, n = m & 1023;
    #pragma unroll
    for (int j = 0; j < 4; ++j) {
      int c = c0 + tx*4 + j;
      float v = acc[i][j] + bias[c];
      int s = c >> 8, rem = c & 255, h = rem >> 5, dd = rem & 31;
      float* dst = (s == 0) ? Qo : (s == 1) ? Ko : Vo;
      dst[(size_t)((bb*HH + h)*NN + n)*HD + dd] = v;
    }
  }
}

// ---------------- fused moire attention ----------------
// one block per (b, h, 64-row q tile); flash-style online softmax
__global__ __launch_bounds__(256) void attn_kernel(
    const float* __restrict__ Q, const float* __restrict__ K,
    const float* __restrict__ V, const float* __restrict__ adj,
    const int* __restrict__ mask, const float* __restrict__ shifts,
    const float* __restrict__ widths, const float* __restrict__ slw,
    float* __restrict__ out)
{
  __shared__ float Qst[HD][68];   // [k][r]
  __shared__ float Kst[HD][68];   // [k][c]
  __shared__ float Vs[64][36];    // [j][d]
  __shared__ float Ps[64][68];    // adj tile -> P tile (in place)
  __shared__ float m_s[64], l_s[64], al_s[64];
  __shared__ int   mq_s[64], mj_s[64];

  const int tid = threadIdx.x;
  const int bh  = blockIdx.x >> 4;      // b*H + h
  const int qt  = blockIdx.x & 15;
  const int b   = bh >> 3, h = bh & 7;
  const int q0  = qt * 64;

  const float sh    = shifts[h];
  const float invw  = 1.0f / fmaxf(widths[h], 0.5f);
  const float slv   = slw[h];
  const float scale = 0.17677669529663687f;   // 1/sqrt(32)
  const float LNEPS = -13.815510557964274f;   // ln(1e-6)

  // Q tile -> LDS transposed (k-major)
  {
    const float* Qg = &Q[(size_t)(bh * NN + q0) * HD];
    #pragma unroll
    for (int it = 0; it < 2; ++it) {
      int e = tid + it * 256;            // 0..511
      int row = e >> 3, kq = e & 7;
      float4 v = *(const float4*)&Qg[row * HD + kq * 4];
      Qst[kq*4+0][row] = v.x; Qst[kq*4+1][row] = v.y;
      Qst[kq*4+2][row] = v.z; Qst[kq*4+3][row] = v.w;
    }
  }
  if (tid < 64) {
    m_s[tid]  = -INFINITY;
    l_s[tid]  = 0.0f;
    mq_s[tid] = mask[b * NN + q0 + tid];
  }

  const int ty = tid >> 4, tx = tid & 15;   // S-phase: rows ty*4+i, cols tx*4+j
  const int pr = tid >> 2;                  // PV-phase row 0..63
  const int pd = (tid & 3) * 8;             // PV-phase d offset

  float o[8] = {};

  for (int jt = 0; jt < 16; ++jt) {
    const int j0 = jt * 64;
    __syncthreads();   // previous PV done with Vs/Ps/al_s
    {
      const float* Kg = &K[(size_t)(bh * NN + j0) * HD];
      #pragma unroll
      for (int it = 0; it < 2; ++it) {
        int e = tid + it * 256;
        int row = e >> 3, kq = e & 7;
        float4 v = *(const float4*)&Kg[row * HD + kq * 4];
        Kst[kq*4+0][row] = v.x; Kst[kq*4+1][row] = v.y;
        Kst[kq*4+2][row] = v.z; Kst[kq*4+3][row] = v.w;
      }
      const float* Vg = &V[(size_t)(bh * NN + j0) * HD];
      #pragma unroll
      for (int it = 0; it < 2; ++it) {
        int e = tid + it * 256;
        int row = e >> 3, dq = e & 7;
        *(float4*)&Vs[row][dq*4] = *(const float4*)&Vg[row * HD + dq * 4];
      }
      const float* Ag = &adj[((size_t)(b * NN + q0)) * NN + j0];
      #pragma unroll
      for (int it = 0; it < 4; ++it) {
        int e = tid + it * 256;            // 0..1023
        int row = e >> 4, cq = e & 15;
        *(float4*)&Ps[row][cq*4] = *(const float4*)&Ag[(size_t)row * NN + cq * 4];
      }
      if (tid < 64) mj_s[tid] = mask[b * NN + j0 + tid];
    }
    __syncthreads();

    // S = Q K^T (64x64), each thread 4x4
    float acc[4][4] = {};
    #pragma unroll
    for (int k = 0; k < HD; ++k) {
      float4 a4 = *(const float4*)&Qst[k][ty*4];
      float4 b4 = *(const float4*)&Kst[k][tx*4];
      float a[4] = {a4.x, a4.y, a4.z, a4.w};
      float bb_[4] = {b4.x, b4.y, b4.z, b4.w};
      #pragma unroll
      for (int i = 0; i < 4; ++i)
        #pragma unroll
        for (int j = 0; j < 4; ++j)
          acc[i][j] += a[i] * bb_[j];
    }

    // moire + self-loop + mask + online softmax
    #pragma unroll
    for (int i = 0; i < 4; ++i) {
      int r  = ty*4 + i;
      int qg = q0 + r;
      bool mqv = (mq_s[r] != 0);
      float rowm = -INFINITY;
      float pv[4];
      #pragma unroll
      for (int j = 0; j < 4; ++j) {
        int c = tx*4 + j;
        float a = Ps[r][c];                  // adj value
        float d = a - sh;
        float val = acc[i][j] * scale + fmaxf(-d * d * invw, LNEPS);
        if (qg == j0 + c) val += slv;
        if (!(mqv && (mj_s[c] != 0))) val = -1000000.0f;
        pv[j] = val;
        rowm = fmaxf(rowm, val);
      }
      rowm = fmaxf(rowm, __shfl_xor(rowm, 1));
      rowm = fmaxf(rowm, __shfl_xor(rowm, 2));
      rowm = fmaxf(rowm, __shfl_xor(rowm, 4));
      rowm = fmaxf(rowm, __shfl_xor(rowm, 8));
      float mold = m_s[r];
      float mnew = fmaxf(mold, rowm);
      float rs = 0.0f;
      #pragma unroll
      for (int j = 0; j < 4; ++j) {
        float p = __expf(pv[j] - mnew);
        Ps[r][tx*4+j] = p;                   // overwrite adj with P
        rs += p;
      }
      rs += __shfl_xor(rs, 1); rs += __shfl_xor(rs, 2);
      rs += __shfl_xor(rs, 4); rs += __shfl_xor(rs, 8);
      if (tx == 0) {
        float alpha = __expf(mold - mnew);   // exp(-inf - finite) = 0 first tile
        m_s[r]  = mnew;
        al_s[r] = alpha;
        l_s[r]  = l_s[r] * alpha + rs;
      }
    }
    __syncthreads();

    // O = alpha*O + P @ V
    float alpha = al_s[pr];
    #pragma unroll
    for (int e = 0; e < 8; ++e) o[e] *= alpha;
    #pragma unroll 4
    for (int j = 0; j < 64; ++j) {
      float p = Ps[pr][j];
      float4 va = *(const float4*)&Vs[j][pd];
      float4 vb = *(const float4*)&Vs[j][pd + 4];
      o[0] += p * va.x; o[1] += p * va.y; o[2] += p * va.z; o[3] += p * va.w;
      o[4] += p * vb.x; o[5] += p * vb.y; o[6] += p * vb.z; o[7] += p * vb.w;
    }
  }

  float invl = 1.0f / l_s[pr];
  float* og = &out[(size_t)(b * NN + q0 + pr) * DM + h * HD + pd];
  float4 oa = {o[0]*invl, o[1]*invl, o[2]*invl, o[3]*invl};
  float4 ob = {o[4]*invl, o[5]*invl, o[6]*invl, o[7]*invl};
  *(float4*)&og[0] = oa;
  *(float4*)&og[4] = ob;
}

extern "C" void kernel_launch(void* const* d_in, const int* in_sizes, int n_in,
                              void* d_out, int out_size, void* d_ws, size_t ws_size,
                              hipStream_t stream) {
  const float* x      = (const float*)d_in[0];
  const float* adj    = (const float*)d_in[1];
  const int*   mask   = (const int*)d_in[2];
  const float* W      = (const float*)d_in[3];
  const float* bias   = (const float*)d_in[4];
  const float* shifts = (const float*)d_in[5];
  const float* widths = (const float*)d_in[6];
  const float* slwp   = (const float*)d_in[7];
  float* out = (float*)d_out;

  float* Qw = (float*)d_ws;                       // [B,H,N,HD]
  float* Kw = Qw + (size_t)BB*HH*NN*HD;
  float* Vw = Kw + (size_t)BB*HH*NN*HD;

  qkv_kernel<<<dim3(TC/64, (BB*NN)/64), 256, 0, stream>>>(x, W, bias, Qw, Kw, Vw);
  attn_kernel<<<dim3(BB*HH*(NN/64)), 256, 0, stream>>>(Qw, Kw, Vw, adj, mask,
                                                       shifts, widths, slwp, out);
}

// Round 2
// 210.342 us; speedup vs baseline: 2.8736x; 2.8736x over previous
//
#include <hip/hip_runtime.h>

#define BB 8
#define NN 1024
#define DM 256
#define HH 8
#define HD 32
#define TC 768   // 3*DM

typedef __bf16 bf16x8 __attribute__((ext_vector_type(8)));
typedef __bf16 bf16x4 __attribute__((ext_vector_type(4)));
typedef float  f32x4  __attribute__((ext_vector_type(4)));

// ---------------- QKV projection GEMM (fp32 compute, bf16 outputs) ----------
// x[B*N, DM] @ W[DM, TC] + bias -> Qb,Kb bf16 [B,H,N,32]; Vt bf16 [B,H,32,N]
__global__ __launch_bounds__(256) void qkv_kernel(
    const float* __restrict__ x, const float* __restrict__ W,
    const float* __restrict__ bias, __bf16* __restrict__ Qb,
    __bf16* __restrict__ Kb, __bf16* __restrict__ Vt)
{
  __shared__ __align__(16) float smem[64 * 68];           // 17.4 KB, multi-use
  float (*As)[68] = (float(*)[68])smem;                   // [16][68] k-major
  float (*Bs)[68] = (float(*)[68])(smem + 16 * 68);       // [16][68]
  float (*T)[68]  = (float(*)[68])smem;                   // [64][68] V transpose

  const int tid = threadIdx.x;
  const int m0 = blockIdx.y * 64;
  const int c0 = blockIdx.x * 64;
  const int ty = tid >> 4, tx = tid & 15;
  const int bb = m0 >> 10, n0 = m0 & 1023;
  float acc[4][4] = {};
  for (int k0 = 0; k0 < DM; k0 += 16) {
    {
      int row = tid >> 2, kq = tid & 3;
      const float4 v = *(const float4*)&x[(size_t)(m0 + row) * DM + k0 + kq * 4];
      As[kq*4+0][row] = v.x; As[kq*4+1][row] = v.y;
      As[kq*4+2][row] = v.z; As[kq*4+3][row] = v.w;
    }
    {
      int k = tid >> 4, cq = tid & 15;
      *(float4*)&Bs[k][cq*4] = *(const float4*)&W[(size_t)(k0 + k) * TC + c0 + cq * 4];
    }
    __syncthreads();
    #pragma unroll
    for (int kk = 0; kk < 16; ++kk) {
      float4 a4 = *(const float4*)&As[kk][ty*4];
      float4 b4 = *(const float4*)&Bs[kk][tx*4];
      float a[4] = {a4.x, a4.y, a4.z, a4.w};
      float b[4] = {b4.x, b4.y, b4.z, b4.w};
      #pragma unroll
      for (int i = 0; i < 4; ++i)
        #pragma unroll
        for (int j = 0; j < 4; ++j)
          acc[i][j] += a[i] * b[j];
    }
    __syncthreads();
  }

  if (c0 < 512) {
    // Q or K tile: direct bf16 stores, 4 consecutive dd per row (8B chunks)
    const int c = c0 + tx * 4;
    const int s = c >> 8;                  // 0=Q, 1=K
    const int h = (c >> 5) & 7, dd = c & 31;
    __bf16* base = (s == 0 ? Qb : Kb);
    #pragma unroll
    for (int i = 0; i < 4; ++i) {
      int n = n0 + ty*4 + i;
      bf16x4 v;
      #pragma unroll
      for (int j = 0; j < 4; ++j) v[j] = (__bf16)(acc[i][j] + bias[c + j]);
      *(bf16x4*)&base[((size_t)((bb*HH + h)*NN + n))*HD + dd] = v;
    }
  } else {
    // V tile: transpose via LDS, store Vt[B,H,32,N] coalesced along n
    __syncthreads();
    #pragma unroll
    for (int i = 0; i < 4; ++i)
      #pragma unroll
      for (int j = 0; j < 4; ++j)
        T[ty*4+i][tx*4+j] = acc[i][j] + bias[c0 + tx*4 + j];
    __syncthreads();
    const int r = tid >> 2, seg = tid & 3;       // r = local c (0..63)
    const int cg = c0 + r;
    const int h = (cg >> 5) & 7, dd = cg & 31;
    __bf16* dst = &Vt[((size_t)((bb*HH + h)*HD + dd))*NN + n0 + seg*16];
    bf16x8 v0, v1;
    #pragma unroll
    for (int i = 0; i < 8; ++i) v0[i] = (__bf16)T[seg*16 + i][r];
    #pragma unroll
    for (int i = 0; i < 8; ++i) v1[i] = (__bf16)T[seg*16 + 8 + i][r];
    *(bf16x8*)&dst[0] = v0;
    *(bf16x8*)&dst[8] = v1;
  }
}

// ---------------- fused moire attention, MFMA ----------------
// block = (b, h, 64-row q tile), 4 waves; wave w owns q rows [w*16, w*16+16)
__global__ __launch_bounds__(256) void attn_kernel(
    const __bf16* __restrict__ Q, const __bf16* __restrict__ K,
    const __bf16* __restrict__ Vt, const float* __restrict__ adj,
    const int* __restrict__ mask, const float* __restrict__ shifts,
    const float* __restrict__ widths, const float* __restrict__ slw,
    float* __restrict__ out)
{
  __shared__ __align__(16) __bf16 Qs[64][40];   // rows padded: 80B, 2-way max
  __shared__ __align__(16) __bf16 Ks[64][40];
  __shared__ __align__(16) __bf16 Vts[32][72];  // V^T tile [d][j]
  __shared__ __align__(16) __bf16 Ps[64][72];   // P tile, per-wave rows
  __shared__ __align__(16) float adjS[64][68];
  __shared__ int mjS[64];

  const int tid  = threadIdx.x;
  const int w    = tid >> 6, lane = tid & 63;
  const int n16  = lane & 15, quad = lane >> 4;
  const int bh   = blockIdx.x >> 4;
  const int qt   = blockIdx.x & 15;
  const int b    = bh >> 3, h = bh & 7;
  const int q0   = qt * 64;

  const float sh    = shifts[h];
  const float invw  = 1.0f / fmaxf(widths[h], 0.5f);
  const float slv   = slw[h];
  const float scale = 0.17677669529663687f;   // 1/sqrt(32)
  const float LNEPS = -13.815510557964274f;   // ln(1e-6)

  // stage Q tile (4 KB contiguous) into LDS
  {
    const __bf16* Qg = Q + (size_t)(bh * NN + q0) * HD;
    int row = tid >> 2, seg = tid & 3;
    *(bf16x8*)&Qs[row][seg*8] = *(const bf16x8*)&Qg[row * HD + seg * 8];
  }
  int mq[4];
  #pragma unroll
  for (int r = 0; r < 4; ++r) mq[r] = mask[b * NN + q0 + w*16 + quad*4 + r];
  __syncthreads();
  const bf16x8 qf = *(const bf16x8*)&Qs[w*16 + n16][quad * 8];

  float m_r[4] = {-3.0e38f, -3.0e38f, -3.0e38f, -3.0e38f};
  float l_r[4] = {};
  f32x4 o0 = {0.f, 0.f, 0.f, 0.f}, o1 = {0.f, 0.f, 0.f, 0.f};
  const f32x4 zero = {0.f, 0.f, 0.f, 0.f};

  for (int jt = 0; jt < 16; ++jt) {
    const int j0 = jt * 64;
    __syncthreads();   // previous iter done with Ks/Vts/adjS
    {
      const __bf16* Kg = K + (size_t)(bh * NN + j0) * HD;
      int row = tid >> 2, seg = tid & 3;
      *(bf16x8*)&Ks[row][seg*8] = *(const bf16x8*)&Kg[row * HD + seg * 8];
      const __bf16* Vg = Vt + (size_t)bh * HD * NN + j0;
      int d = tid >> 3, sg = tid & 7;
      *(bf16x8*)&Vts[d][sg*8] = *(const bf16x8*)&Vg[(size_t)d * NN + sg * 8];
      const float* Ag = adj + ((size_t)(b * NN + q0)) * NN + j0;
      #pragma unroll
      for (int it = 0; it < 4; ++it) {
        int e = tid + it * 256, row2 = e >> 4, cq = e & 15;
        *(float4*)&adjS[row2][cq*4] = *(const float4*)&Ag[(size_t)row2 * NN + cq * 4];
      }
      if (tid < 64) mjS[tid] = mask[b * NN + j0 + tid];
    }
    __syncthreads();

    // S = Q K^T : wave w computes rows [w*16, w*16+16) x 64 cols, 4 MFMAs
    f32x4 s[4];
    #pragma unroll
    for (int cb = 0; cb < 4; ++cb) {
      bf16x8 kf = *(const bf16x8*)&Ks[cb*16 + n16][quad * 8];
      s[cb] = __builtin_amdgcn_mfma_f32_16x16x32_bf16(qf, kf, zero, 0, 0, 0);
    }
    int mj[4];
    #pragma unroll
    for (int cb = 0; cb < 4; ++cb) mj[cb] = mjS[cb*16 + n16];

    // moire + self-loop + mask + online softmax (fp32, state in regs)
    float alpha[4];
    #pragma unroll
    for (int r = 0; r < 4; ++r) {
      const int rowq = w*16 + quad*4 + r;       // C/D layout: row = quad*4+reg
      const int qg = q0 + rowq;
      float v[4], rowm = -3.0e38f;
      #pragma unroll
      for (int cb = 0; cb < 4; ++cb) {
        float a = adjS[rowq][cb*16 + n16];
        float d = a - sh;
        float val = s[cb][r] * scale + fmaxf(-d * d * invw, LNEPS);
        if (j0 + cb*16 + n16 == qg) val += slv;
        if (!(mq[r] && mj[cb])) val = -1000000.0f;
        v[cb] = val;
        rowm = fmaxf(rowm, val);
      }
      rowm = fmaxf(rowm, __shfl_xor(rowm, 1));
      rowm = fmaxf(rowm, __shfl_xor(rowm, 2));
      rowm = fmaxf(rowm, __shfl_xor(rowm, 4));
      rowm = fmaxf(rowm, __shfl_xor(rowm, 8));
      float mnew = fmaxf(m_r[r], rowm);
      float rs = 0.0f;
      #pragma unroll
      for (int cb = 0; cb < 4; ++cb) {
        float p = __expf(v[cb] - mnew);
        rs += p;
        Ps[rowq][cb*16 + n16] = (__bf16)p;
      }
      rs += __shfl_xor(rs, 1); rs += __shfl_xor(rs, 2);
      rs += __shfl_xor(rs, 4); rs += __shfl_xor(rs, 8);
      alpha[r] = __expf(m_r[r] - mnew);
      m_r[r] = mnew;
      l_r[r] = l_r[r] * alpha[r] + rs;
    }

    // O = alpha*O + P @ V  (A=P from own wave's LDS rows, B=V^T tile)
    #pragma unroll
    for (int r = 0; r < 4; ++r) { o0[r] *= alpha[r]; o1[r] *= alpha[r]; }
    bf16x8 a0  = *(const bf16x8*)&Ps[w*16 + n16][quad * 8];        // k 0..31
    bf16x8 a1  = *(const bf16x8*)&Ps[w*16 + n16][32 + quad * 8];   // k 32..63
    bf16x8 b00 = *(const bf16x8*)&Vts[n16][quad * 8];              // d 0..15
    bf16x8 b01 = *(const bf16x8*)&Vts[n16][32 + quad * 8];
    bf16x8 b10 = *(const bf16x8*)&Vts[16 + n16][quad * 8];         // d 16..31
    bf16x8 b11 = *(const bf16x8*)&Vts[16 + n16][32 + quad * 8];
    o0 = __builtin_amdgcn_mfma_f32_16x16x32_bf16(a0, b00, o0, 0, 0, 0);
    o0 = __builtin_amdgcn_mfma_f32_16x16x32_bf16(a1, b01, o0, 0, 0, 0);
    o1 = __builtin_amdgcn_mfma_f32_16x16x32_bf16(a0, b10, o1, 0, 0, 0);
    o1 = __builtin_amdgcn_mfma_f32_16x16x32_bf16(a1, b11, o1, 0, 0, 0);
  }

  #pragma unroll
  for (int r = 0; r < 4; ++r) {
    float invl = 1.0f / l_r[r];
    int n = q0 + w*16 + quad*4 + r;
    float* og = out + ((size_t)(b * NN + n)) * DM + h * HD;
    og[n16]      = o0[r] * invl;
    og[16 + n16] = o1[r] * invl;
  }
}

extern "C" void kernel_launch(void* const* d_in, const int* in_sizes, int n_in,
                              void* d_out, int out_size, void* d_ws, size_t ws_size,
                              hipStream_t stream) {
  const float* x      = (const float*)d_in[0];
  const float* adj    = (const float*)d_in[1];
  const int*   mask   = (const int*)d_in[2];
  const float* W      = (const float*)d_in[3];
  const float* bias   = (const float*)d_in[4];
  const float* shifts = (const float*)d_in[5];
  const float* widths = (const float*)d_in[6];
  const float* slwp   = (const float*)d_in[7];
  float* out = (float*)d_out;

  __bf16* Qb = (__bf16*)d_ws;                       // [B,H,N,32]
  __bf16* Kb = Qb + (size_t)BB*HH*NN*HD;            // [B,H,N,32]
  __bf16* Vt = Kb + (size_t)BB*HH*NN*HD;            // [B,H,32,N]

  qkv_kernel<<<dim3(TC/64, (BB*NN)/64), 256, 0, stream>>>(x, W, bias, Qb, Kb, Vt);
  attn_kernel<<<dim3(BB*HH*(NN/64)), 256, 0, stream>>>(Qb, Kb, Vt, adj, mask,
                                                       shifts, widths, slwp, out);
}

// Round 3
// 163.484 us; speedup vs baseline: 3.6972x; 1.2866x over previous
//
#include <hip/hip_runtime.h>

#define BB 8
#define NN 1024
#define DM 256
#define HH 8
#define HD 32
#define TC 768   // 3*DM

typedef __bf16 bf16x8 __attribute__((ext_vector_type(8)));
typedef float  f32x4  __attribute__((ext_vector_type(4)));

// ---------------- QKV projection: bf16 MFMA GEMM ----------------
// x[8192,256] fp32 (cast in staging) @ W[256,768] fp32 (transposed in staging)
// -> Qb,Kb bf16 [B,H,N,32]; Vt bf16 [B,H,32,N]
__global__ __launch_bounds__(256, 4) void qkv_gemm(
    const float* __restrict__ x, const float* __restrict__ W,
    const float* __restrict__ bias, __bf16* __restrict__ Qb,
    __bf16* __restrict__ Kb, __bf16* __restrict__ Vt)
{
  __shared__ __align__(16) __bf16 As[128][40];   // [m][k] 10.0 KB
  __shared__ __align__(16) __bf16 Bs[64][40];    // [c][k]  5.0 KB
  const int tid  = threadIdx.x;
  const int w    = tid >> 6, lane = tid & 63;
  const int n16  = lane & 15, quad = lane >> 4;
  const int m0   = blockIdx.y * 128, c0 = blockIdx.x * 64;

  const int arow = tid >> 1, ahalf = tid & 1;    // A staging: 128 rows x 32 B
  const int bc   = tid & 63, bkh = tid >> 6;     // B staging: 64 c x 4 k-chunks

  f32x4 acc[2][4] = {};
  const f32x4 zero = {0.f, 0.f, 0.f, 0.f};
  (void)zero;

  for (int k0 = 0; k0 < DM; k0 += 32) {
    {  // A tile: coalesced fp32 reads, cast, row-major bf16 LDS
      const float* xa = &x[(size_t)(m0 + arow) * DM + k0 + ahalf * 16];
      float4 f0 = *(const float4*)&xa[0];
      float4 f1 = *(const float4*)&xa[4];
      float4 f2 = *(const float4*)&xa[8];
      float4 f3 = *(const float4*)&xa[12];
      bf16x8 a0, a1;
      a0[0]=(__bf16)f0.x; a0[1]=(__bf16)f0.y; a0[2]=(__bf16)f0.z; a0[3]=(__bf16)f0.w;
      a0[4]=(__bf16)f1.x; a0[5]=(__bf16)f1.y; a0[6]=(__bf16)f1.z; a0[7]=(__bf16)f1.w;
      a1[0]=(__bf16)f2.x; a1[1]=(__bf16)f2.y; a1[2]=(__bf16)f2.z; a1[3]=(__bf16)f2.w;
      a1[4]=(__bf16)f3.x; a1[5]=(__bf16)f3.y; a1[6]=(__bf16)f3.z; a1[7]=(__bf16)f3.w;
      *(bf16x8*)&As[arow][ahalf*16]     = a0;
      *(bf16x8*)&As[arow][ahalf*16 + 8] = a1;
    }
    {  // B tile: read W columns (coalesced along c), write [c][k] contiguous
      bf16x8 bv;
      #pragma unroll
      for (int j = 0; j < 8; ++j)
        bv[j] = (__bf16)W[(size_t)(k0 + bkh*8 + j) * TC + c0 + bc];
      *(bf16x8*)&Bs[bc][bkh*8] = bv;
    }
    __syncthreads();
    bf16x8 af0 = *(const bf16x8*)&As[w*32 + n16][quad*8];
    bf16x8 af1 = *(const bf16x8*)&As[w*32 + 16 + n16][quad*8];
    #pragma unroll
    for (int cb = 0; cb < 4; ++cb) {
      bf16x8 bf = *(const bf16x8*)&Bs[cb*16 + n16][quad*8];
      acc[0][cb] = __builtin_amdgcn_mfma_f32_16x16x32_bf16(af0, bf, acc[0][cb], 0, 0, 0);
      acc[1][cb] = __builtin_amdgcn_mfma_f32_16x16x32_bf16(af1, bf, acc[1][cb], 0, 0, 0);
    }
    __syncthreads();
  }

  // epilogue: C row = quad*4+reg, col = n16; route per 256-col section (uniform)
  #pragma unroll
  for (int cb = 0; cb < 4; ++cb) {
    const int c = c0 + cb*16 + n16;
    const float bv = bias[c];
    const int s = c >> 8, h = (c >> 5) & 7, dd = c & 31;
    #pragma unroll
    for (int mb = 0; mb < 2; ++mb) {
      #pragma unroll
      for (int r = 0; r < 4; ++r) {
        const int m = m0 + w*32 + mb*16 + quad*4 + r;
        const int bb = m >> 10, n = m & 1023;
        const __bf16 v = (__bf16)(acc[mb][cb][r] + bv);
        if (s == 2)
          Vt[((size_t)((bb*HH + h)*HD + dd))*NN + n] = v;
        else
          ((s == 0) ? Qb : Kb)[((size_t)((bb*HH + h)*NN + n))*HD + dd] = v;
      }
    }
  }
}

// ---------------- fused moire attention, MFMA, fixed-max softmax ------------
// block = (b, h, 64-row q tile), 4 waves; wave w owns q rows [w*16, w*16+16)
__global__ __launch_bounds__(256, 4) void attn_kernel(
    const __bf16* __restrict__ Q, const __bf16* __restrict__ K,
    const __bf16* __restrict__ Vt, const float* __restrict__ adj,
    const int* __restrict__ mask, const float* __restrict__ shifts,
    const float* __restrict__ widths, const float* __restrict__ slw,
    float* __restrict__ out)
{
  __shared__ __align__(16) __bf16 Qs[64][40];        // 5.0 KB
  __shared__ __align__(16) __bf16 Ks[2][64][40];     // 10.0 KB (double buf)
  __shared__ __align__(16) __bf16 Vts[2][32][72];    //  9.0 KB (double buf)
  __shared__ __align__(16) __bf16 Ps[64][72];        //  9.0 KB (wave-private rows)

  const int tid  = threadIdx.x;
  const int w    = tid >> 6, lane = tid & 63;
  const int n16  = lane & 15, quad = lane >> 4;
  const int bh   = blockIdx.x >> 4, qt = blockIdx.x & 15;
  const int b    = bh >> 3, h = bh & 7;
  const int q0   = qt * 64;

  // exp2-domain constants (all pre-multiplied by log2(e))
  const float L2E   = 1.4426950408889634f;
  const float sh    = shifts[h];
  const float ninvw = -L2E / fmaxf(widths[h], 0.5f);
  const float slv   = slw[h] * L2E;
  const float scl   = 0.17677669529663687f * L2E;   // 1/sqrt(32) * log2e
  const float LGEPS = -19.931568569324174f;          // log2(1e-6)
  const float MASKV = -28.0f;  // constant => fully-masked rows come out uniform

  const int srow = tid >> 2, sseg = tid & 3;   // Q/K staging map
  const int vd   = tid >> 3, vsg  = tid & 7;   // Vt staging map

  {
    const __bf16* Qg = Q + (size_t)(bh*NN + q0)*HD;
    *(bf16x8*)&Qs[srow][sseg*8] = *(const bf16x8*)&Qg[srow*HD + sseg*8];
  }
  const __bf16* Kg = K + (size_t)bh*NN*HD;
  const __bf16* Vg = Vt + (size_t)bh*HD*NN;
  {  // prefetch j-tile 0 into buffer 0
    bf16x8 k0v = *(const bf16x8*)&Kg[srow*HD + sseg*8];
    bf16x8 v0v = *(const bf16x8*)&Vg[(size_t)vd*NN + vsg*8];
    *(bf16x8*)&Ks[0][srow][sseg*8] = k0v;
    *(bf16x8*)&Vts[0][vd][vsg*8]   = v0v;
  }
  int mq[4];
  #pragma unroll
  for (int r = 0; r < 4; ++r) mq[r] = mask[b*NN + q0 + w*16 + quad*4 + r];
  __syncthreads();

  const bf16x8 qf = *(const bf16x8*)&Qs[w*16 + n16][quad*8];
  const f32x4 zero = {0.f, 0.f, 0.f, 0.f};
  float l_r[4] = {0.f, 0.f, 0.f, 0.f};
  f32x4 o0 = zero, o1 = zero;

  const float* adjRow = adj + ((size_t)(b*NN + q0 + w*16 + quad*4))*NN;
  const int*   mrow   = mask + b*NN;

  #pragma unroll 2
  for (int jt = 0; jt < 16; ++jt) {
    const int cur = jt & 1;
    const int j0  = jt * 64;

    bf16x8 kn, vn;
    if (jt < 15) {   // prefetch next tile to registers (hidden under compute)
      kn = *(const bf16x8*)&Kg[(j0 + 64 + srow)*HD + sseg*8];
      vn = *(const bf16x8*)&Vg[(size_t)vd*NN + j0 + 64 + vsg*8];
    }

    // adj + mask direct from global (L2-hot; no LDS round trip)
    int mj[4];
    #pragma unroll
    for (int cb = 0; cb < 4; ++cb) mj[cb] = mrow[j0 + cb*16 + n16];
    float av[4][4];
    #pragma unroll
    for (int r = 0; r < 4; ++r)
      #pragma unroll
      for (int cb = 0; cb < 4; ++cb)
        av[r][cb] = adjRow[(size_t)r*NN + j0 + cb*16 + n16];

    // S = Q K^T (16 q-rows x 64 cols per wave)
    f32x4 s[4];
    #pragma unroll
    for (int cb = 0; cb < 4; ++cb) {
      bf16x8 kf = *(const bf16x8*)&Ks[cur][cb*16 + n16][quad*8];
      s[cb] = __builtin_amdgcn_mfma_f32_16x16x32_bf16(qf, kf, zero, 0, 0, 0);
    }

    // moire + self-loop + mask + exp2 (fixed max = 0; no reductions)
    #pragma unroll
    for (int r = 0; r < 4; ++r) {
      const int qg = q0 + w*16 + quad*4 + r;
      #pragma unroll
      for (int cb = 0; cb < 4; ++cb) {
        float d   = av[r][cb] - sh;
        float mo  = fmaxf(d*d*ninvw, LGEPS);
        float val = fmaf(s[cb][r], scl, mo);
        if (j0 + cb*16 + n16 == qg) val += slv;
        bool ok = (mq[r] != 0) && (mj[cb] != 0);
        val = ok ? val : MASKV;
        float p = exp2f(val);
        l_r[r] += p;
        Ps[w*16 + quad*4 + r][cb*16 + n16] = (__bf16)p;
      }
    }

    // O += P @ V
    bf16x8 a0  = *(const bf16x8*)&Ps[w*16 + n16][quad*8];
    bf16x8 a1  = *(const bf16x8*)&Ps[w*16 + n16][32 + quad*8];
    bf16x8 b00 = *(const bf16x8*)&Vts[cur][n16][quad*8];
    bf16x8 b01 = *(const bf16x8*)&Vts[cur][n16][32 + quad*8];
    bf16x8 b10 = *(const bf16x8*)&Vts[cur][16 + n16][quad*8];
    bf16x8 b11 = *(const bf16x8*)&Vts[cur][16 + n16][32 + quad*8];
    o0 = __builtin_amdgcn_mfma_f32_16x16x32_bf16(a0, b00, o0, 0, 0, 0);
    o0 = __builtin_amdgcn_mfma_f32_16x16x32_bf16(a1, b01, o0, 0, 0, 0);
    o1 = __builtin_amdgcn_mfma_f32_16x16x32_bf16(a0, b10, o1, 0, 0, 0);
    o1 = __builtin_amdgcn_mfma_f32_16x16x32_bf16(a1, b11, o1, 0, 0, 0);

    if (jt < 15) {   // publish prefetched tile to the other buffer
      *(bf16x8*)&Ks[1 - cur][srow][sseg*8] = kn;
      *(bf16x8*)&Vts[1 - cur][vd][vsg*8]   = vn;
    }
    __syncthreads();   // single barrier per j-tile
  }

  // final row-sum reduce (only cross-lane op in the kernel) + store
  #pragma unroll
  for (int r = 0; r < 4; ++r) {
    float l = l_r[r];
    l += __shfl_xor(l, 1); l += __shfl_xor(l, 2);
    l += __shfl_xor(l, 4); l += __shfl_xor(l, 8);
    const float invl = 1.0f / l;
    const int n = q0 + w*16 + quad*4 + r;
    float* og = out + ((size_t)(b*NN + n))*DM + h*HD;
    og[n16]      = o0[r] * invl;
    og[16 + n16] = o1[r] * invl;
  }
}

extern "C" void kernel_launch(void* const* d_in, const int* in_sizes, int n_in,
                              void* d_out, int out_size, void* d_ws, size_t ws_size,
                              hipStream_t stream) {
  const float* x      = (const float*)d_in[0];
  const float* adj    = (const float*)d_in[1];
  const int*   mask   = (const int*)d_in[2];
  const float* W      = (const float*)d_in[3];
  const float* bias   = (const float*)d_in[4];
  const float* shifts = (const float*)d_in[5];
  const float* widths = (const float*)d_in[6];
  const float* slwp   = (const float*)d_in[7];
  float* out = (float*)d_out;

  __bf16* Qb = (__bf16*)d_ws;                       // [B,H,N,32]
  __bf16* Kb = Qb + (size_t)BB*HH*NN*HD;            // [B,H,N,32]
  __bf16* Vt = Kb + (size_t)BB*HH*NN*HD;            // [B,H,32,N]

  qkv_gemm<<<dim3(TC/64, (BB*NN)/128), 256, 0, stream>>>(x, W, bias, Qb, Kb, Vt);
  attn_kernel<<<dim3(BB*HH*(NN/64)), 256, 0, stream>>>(Qb, Kb, Vt, adj, mask,
                                                       shifts, widths, slwp, out);
}

// Round 4
// 151.754 us; speedup vs baseline: 3.9830x; 1.0773x over previous
//
#include <hip/hip_runtime.h>

#define BB 8
#define NN 1024
#define DM 256
#define HH 8
#define HD 32
#define TC 768   // 3*DM

typedef __bf16 bf16x8 __attribute__((ext_vector_type(8)));
typedef __bf16 bf16x4 __attribute__((ext_vector_type(4)));
typedef float  f32x4  __attribute__((ext_vector_type(4)));

// ---------------- QKV projection: bf16 MFMA GEMM ----------------
// x[8192,256] fp32 @ W[256,768] fp32 -> Qb,Kb bf16 [B,H,N,32]; Vt bf16 [B,H,32,N]
// Epilogue routes C through LDS for vectorized, coalesced bf16x8 stores.
__global__ __launch_bounds__(256, 4) void qkv_gemm(
    const float* __restrict__ x, const float* __restrict__ W,
    const float* __restrict__ bias, __bf16* __restrict__ Qb,
    __bf16* __restrict__ Kb, __bf16* __restrict__ Vt)
{
  __shared__ __align__(16) char U[18432];          // As+Bs staging, then C tile
  __bf16* As = (__bf16*)U;                         // [128][40]
  __bf16* Bs = (__bf16*)(U + 10240);               // [64][40]

  const int tid  = threadIdx.x;
  const int w    = tid >> 6, lane = tid & 63;
  const int n16  = lane & 15, quad = lane >> 4;
  const int m0   = blockIdx.y * 128, c0 = blockIdx.x * 64;
  const int bb   = m0 >> 10, n0 = m0 & 1023;

  const int arow = tid >> 1, ahalf = tid & 1;
  const int bc   = tid & 63, bkh = tid >> 6;

  f32x4 acc[2][4] = {};

  for (int k0 = 0; k0 < DM; k0 += 32) {
    {  // A tile: coalesced fp32 reads, cast, row-major bf16 LDS
      const float* xa = &x[(size_t)(m0 + arow) * DM + k0 + ahalf * 16];
      float4 f0 = *(const float4*)&xa[0];
      float4 f1 = *(const float4*)&xa[4];
      float4 f2 = *(const float4*)&xa[8];
      float4 f3 = *(const float4*)&xa[12];
      bf16x8 a0, a1;
      a0[0]=(__bf16)f0.x; a0[1]=(__bf16)f0.y; a0[2]=(__bf16)f0.z; a0[3]=(__bf16)f0.w;
      a0[4]=(__bf16)f1.x; a0[5]=(__bf16)f1.y; a0[6]=(__bf16)f1.z; a0[7]=(__bf16)f1.w;
      a1[0]=(__bf16)f2.x; a1[1]=(__bf16)f2.y; a1[2]=(__bf16)f2.z; a1[3]=(__bf16)f2.w;
      a1[4]=(__bf16)f3.x; a1[5]=(__bf16)f3.y; a1[6]=(__bf16)f3.z; a1[7]=(__bf16)f3.w;
      *(bf16x8*)&As[arow*40 + ahalf*16]     = a0;
      *(bf16x8*)&As[arow*40 + ahalf*16 + 8] = a1;
    }
    {  // B tile: W columns (coalesced along c), [c][k] contiguous in LDS
      bf16x8 bv;
      #pragma unroll
      for (int j = 0; j < 8; ++j)
        bv[j] = (__bf16)W[(size_t)(k0 + bkh*8 + j) * TC + c0 + bc];
      *(bf16x8*)&Bs[bc*40 + bkh*8] = bv;
    }
    __syncthreads();
    bf16x8 af0 = *(const bf16x8*)&As[(w*32 + n16)*40 + quad*8];
    bf16x8 af1 = *(const bf16x8*)&As[(w*32 + 16 + n16)*40 + quad*8];
    #pragma unroll
    for (int cb = 0; cb < 4; ++cb) {
      bf16x8 bf = *(const bf16x8*)&Bs[(cb*16 + n16)*40 + quad*8];
      acc[0][cb] = __builtin_amdgcn_mfma_f32_16x16x32_bf16(af0, bf, acc[0][cb], 0, 0, 0);
      acc[1][cb] = __builtin_amdgcn_mfma_f32_16x16x32_bf16(af1, bf, acc[1][cb], 0, 0, 0);
    }
    __syncthreads();   // also protects U reuse below after last iter
  }

  float bv[4];
  #pragma unroll
  for (int cb = 0; cb < 4; ++cb) bv[cb] = bias[c0 + cb*16 + n16];

  if (c0 < 512) {
    // Q/K tile: C -> LDS [128][72], then coalesced bf16x8 row stores
    __bf16* Ct = (__bf16*)U;
    #pragma unroll
    for (int cb = 0; cb < 4; ++cb)
      #pragma unroll
      for (int mb = 0; mb < 2; ++mb)
        #pragma unroll
        for (int r = 0; r < 4; ++r)
          Ct[(w*32 + mb*16 + quad*4 + r)*72 + cb*16 + n16] =
              (__bf16)(acc[mb][cb][r] + bv[cb]);
    __syncthreads();
    const int chunk = tid & 3, hh = (tid >> 2) & 1, rbase = tid >> 3;
    const int c_head = c0 + hh*32;
    const int h = (c_head >> 5) & 7;
    __bf16* base = (c_head >> 8) ? Kb : Qb;
    #pragma unroll
    for (int it = 0; it < 4; ++it) {
      int rl = rbase + it*32;
      bf16x8 v = *(const bf16x8*)&Ct[rl*72 + hh*32 + chunk*8];
      *(bf16x8*)&base[((size_t)((bb*HH + h)*NN + n0 + rl))*HD + chunk*8] = v;
    }
  } else {
    // V tile: C^T -> LDS [64][136], then coalesced bf16x8 stores along n
    __bf16* CtT = (__bf16*)U;
    #pragma unroll
    for (int cb = 0; cb < 4; ++cb)
      #pragma unroll
      for (int mb = 0; mb < 2; ++mb) {
        bf16x4 t;
        #pragma unroll
        for (int r = 0; r < 4; ++r) t[r] = (__bf16)(acc[mb][cb][r] + bv[cb]);
        *(bf16x4*)&CtT[(cb*16 + n16)*136 + w*32 + mb*16 + quad*4] = t;
      }
    __syncthreads();
    const int col = tid >> 2, sg = tid & 3;
    const int c = c0 + col;
    const int h = (c >> 5) & 7, dd = c & 31;
    __bf16* dst = &Vt[((size_t)((bb*HH + h)*HD + dd))*NN + n0 + sg*32];
    const __bf16* srcp = &CtT[col*136 + sg*32];
    #pragma unroll
    for (int q2 = 0; q2 < 4; ++q2)
      *(bf16x8*)&dst[q2*8] = *(const bf16x8*)&srcp[q2*8];
  }
}

// ---------------- fused moire attention, MFMA, fixed-max softmax ------------
// block = (b, h, 64-q-row tile, j-part); wave w owns q rows [w*16, w*16+16)
template <int NJT, bool SPLIT>
__global__ __launch_bounds__(256, 4) void attn_kernel(
    const __bf16* __restrict__ Q, const __bf16* __restrict__ K,
    const __bf16* __restrict__ Vt, const float* __restrict__ adj,
    const int* __restrict__ mask, const float* __restrict__ shifts,
    const float* __restrict__ widths, const float* __restrict__ slw,
    float* __restrict__ out, float* __restrict__ Opart,
    float* __restrict__ lpart)
{
  __shared__ __align__(16) char U[9216];             // Qs (init) then Ps
  __bf16 (*Qs)[40] = (__bf16(*)[40])U;
  __bf16 (*Ps)[72] = (__bf16(*)[72])U;
  __shared__ __align__(16) __bf16 Ks[2][64][40];     // 10.0 KB double buf
  __shared__ __align__(16) __bf16 Vts[2][32][72];    //  9.0 KB double buf

  const int tid  = threadIdx.x;
  const int w    = tid >> 6, lane = tid & 63;
  const int n16  = lane & 15, quad = lane >> 4;
  const int bh   = blockIdx.x >> 4, qt = blockIdx.x & 15;
  const int part = blockIdx.y;
  const int b    = bh >> 3, h = bh & 7;
  const int q0   = qt * 64;
  const int jbase = part * NJT * 64;

  const float L2E   = 1.4426950408889634f;
  const float sh    = shifts[h];
  const float ninvw = -L2E / fmaxf(widths[h], 0.5f);
  const float slv   = slw[h] * L2E;
  const float scl   = 0.17677669529663687f * L2E;
  const float LGEPS = -19.931568569324174f;          // log2(1e-6)
  const float MASKV = -28.0f;   // constant: fully-masked rows stay uniform

  const int srow = tid >> 2, sseg = tid & 3;
  const int vd   = tid >> 3, vsg  = tid & 7;

  {
    const __bf16* Qg = Q + (size_t)(bh*NN + q0)*HD;
    *(bf16x8*)&Qs[srow][sseg*8] = *(const bf16x8*)&Qg[srow*HD + sseg*8];
  }
  const __bf16* Kg = K + (size_t)bh*NN*HD;
  const __bf16* Vg = Vt + (size_t)bh*HD*NN;
  {  // prefetch j-tile 0 of this part into buffer 0
    *(bf16x8*)&Ks[0][srow][sseg*8] =
        *(const bf16x8*)&Kg[(jbase + srow)*HD + sseg*8];
    *(bf16x8*)&Vts[0][vd][vsg*8] =
        *(const bf16x8*)&Vg[(size_t)vd*NN + jbase + vsg*8];
  }
  int mq[4];
  #pragma unroll
  for (int r = 0; r < 4; ++r) mq[r] = mask[b*NN + q0 + w*16 + quad*4 + r];
  __syncthreads();
  const bf16x8 qf = *(const bf16x8*)&Qs[w*16 + n16][quad*8];
  __syncthreads();   // Qs dead; U becomes Ps

  const f32x4 zero = {0.f, 0.f, 0.f, 0.f};
  float l_r[4] = {0.f, 0.f, 0.f, 0.f};
  f32x4 o0 = zero, o1 = zero;

  const float* adjRow = adj + ((size_t)(b*NN + q0 + w*16 + quad*4))*NN;
  const int*   mrow   = mask + b*NN;

  #pragma unroll 2
  for (int jtl = 0; jtl < NJT; ++jtl) {
    const int cur = jtl & 1;
    const int j0  = jbase + jtl * 64;

    bf16x8 kn, vn;
    if (jtl < NJT - 1) {   // prefetch next tile into regs
      kn = *(const bf16x8*)&Kg[(j0 + 64 + srow)*HD + sseg*8];
      vn = *(const bf16x8*)&Vg[(size_t)vd*NN + j0 + 64 + vsg*8];
    }

    int mj[4];
    #pragma unroll
    for (int cb = 0; cb < 4; ++cb) mj[cb] = mrow[j0 + cb*16 + n16];
    float av[4][4];
    #pragma unroll
    for (int r = 0; r < 4; ++r)
      #pragma unroll
      for (int cb = 0; cb < 4; ++cb)
        av[r][cb] = adjRow[(size_t)r*NN + j0 + cb*16 + n16];

    f32x4 s[4];
    #pragma unroll
    for (int cb = 0; cb < 4; ++cb) {
      bf16x8 kf = *(const bf16x8*)&Ks[cur][cb*16 + n16][quad*8];
      s[cb] = __builtin_amdgcn_mfma_f32_16x16x32_bf16(qf, kf, zero, 0, 0, 0);
    }

    const bool diagtile = ((part * NJT + jtl) == qt);   // uniform branch
    #pragma unroll
    for (int r = 0; r < 4; ++r) {
      const int rowl = w*16 + quad*4 + r;
      #pragma unroll
      for (int cb = 0; cb < 4; ++cb) {
        float d   = av[r][cb] - sh;
        float mo  = fmaxf(d*d*ninvw, LGEPS);
        float val = fmaf(s[cb][r], scl, mo);
        if (diagtile && (cb*16 + n16 == rowl)) val += slv;
        bool ok = (mq[r] != 0) && (mj[cb] != 0);
        val = ok ? val : MASKV;
        float p = __builtin_amdgcn_exp2f(val);
        l_r[r] += p;
        Ps[rowl][cb*16 + n16] = (__bf16)p;
      }
    }

    bf16x8 a0  = *(const bf16x8*)&Ps[w*16 + n16][quad*8];
    bf16x8 a1  = *(const bf16x8*)&Ps[w*16 + n16][32 + quad*8];
    bf16x8 b00 = *(const bf16x8*)&Vts[cur][n16][quad*8];
    bf16x8 b01 = *(const bf16x8*)&Vts[cur][n16][32 + quad*8];
    bf16x8 b10 = *(const bf16x8*)&Vts[cur][16 + n16][quad*8];
    bf16x8 b11 = *(const bf16x8*)&Vts[cur][16 + n16][32 + quad*8];
    o0 = __builtin_amdgcn_mfma_f32_16x16x32_bf16(a0, b00, o0, 0, 0, 0);
    o0 = __builtin_amdgcn_mfma_f32_16x16x32_bf16(a1, b01, o0, 0, 0, 0);
    o1 = __builtin_amdgcn_mfma_f32_16x16x32_bf16(a0, b10, o1, 0, 0, 0);
    o1 = __builtin_amdgcn_mfma_f32_16x16x32_bf16(a1, b11, o1, 0, 0, 0);

    if (jtl < NJT - 1) {
      *(bf16x8*)&Ks[1 - cur][srow][sseg*8] = kn;
      *(bf16x8*)&Vts[1 - cur][vd][vsg*8]   = vn;
    }
    __syncthreads();   // single barrier per j-tile
  }

  #pragma unroll
  for (int r = 0; r < 4; ++r) {
    float l = l_r[r];
    l += __shfl_xor(l, 1); l += __shfl_xor(l, 2);
    l += __shfl_xor(l, 4); l += __shfl_xor(l, 8);
    const int n = q0 + w*16 + quad*4 + r;
    if (SPLIT) {
      float* og = Opart + ((size_t)(part*BB*HH + bh)*NN + n)*HD;
      og[n16]      = o0[r];
      og[16 + n16] = o1[r];
      if (n16 == 0) lpart[(size_t)(part*BB*HH + bh)*NN + n] = l;
    } else {
      const float invl = 1.0f / l;
      float* og = out + ((size_t)(b*NN + n))*DM + h*HD;
      og[n16]      = o0[r] * invl;
      og[16 + n16] = o1[r] * invl;
    }
  }
}

// combine: out = (O0 + O1) / (l0 + l1), coalesced float4 over output layout
__global__ __launch_bounds__(256) void combine_kernel(
    const float* __restrict__ Opart, const float* __restrict__ lpart,
    float* __restrict__ out)
{
  const size_t e = (size_t)blockIdx.x * 256 + threadIdx.x;  // float4 index
  const int c = (int)((e << 2) & 255);
  const int n = (int)((e >> 6) & 1023);
  const int b = (int)(e >> 16);
  const int h = c >> 5, d = c & 31;
  const size_t row = (size_t)(b*HH + h)*NN + n;
  const size_t i0  = row*HD + d;
  const size_t ps  = (size_t)BB*HH*NN*HD;
  const float4 a0 = *(const float4*)&Opart[i0];
  const float4 a1 = *(const float4*)&Opart[ps + i0];
  const float  l  = lpart[row] + lpart[(size_t)BB*HH*NN + row];
  const float invl = 1.0f / l;
  float4 o = {(a0.x + a1.x)*invl, (a0.y + a1.y)*invl,
              (a0.z + a1.z)*invl, (a0.w + a1.w)*invl};
  *(float4*)&out[((size_t)(b*NN + n))*DM + c] = o;
}

extern "C" void kernel_launch(void* const* d_in, const int* in_sizes, int n_in,
                              void* d_out, int out_size, void* d_ws, size_t ws_size,
                              hipStream_t stream) {
  const float* x      = (const float*)d_in[0];
  const float* adj    = (const float*)d_in[1];
  const int*   mask   = (const int*)d_in[2];
  const float* W      = (const float*)d_in[3];
  const float* bias   = (const float*)d_in[4];
  const float* shifts = (const float*)d_in[5];
  const float* widths = (const float*)d_in[6];
  const float* slwp   = (const float*)d_in[7];
  float* out = (float*)d_out;

  const size_t BHND = (size_t)BB*HH*NN*HD;          // 2,097,152
  __bf16* Qb = (__bf16*)d_ws;                        // [B,H,N,32]
  __bf16* Kb = Qb + BHND;                            // [B,H,N,32]
  __bf16* Vt = Kb + BHND;                            // [B,H,32,N]
  float*  Opart = (float*)((char*)d_ws + 3*BHND*sizeof(__bf16));
  float*  lpart = Opart + 2*BHND;
  const size_t need = 3*BHND*2 + 2*BHND*4 + 2*(size_t)BB*HH*NN*4;

  qkv_gemm<<<dim3(TC/64, (BB*NN)/128), 256, 0, stream>>>(x, W, bias, Qb, Kb, Vt);

  if (ws_size >= need) {
    attn_kernel<8, true><<<dim3(BB*HH*(NN/64), 2), 256, 0, stream>>>(
        Qb, Kb, Vt, adj, mask, shifts, widths, slwp, out, Opart, lpart);
    combine_kernel<<<(int)(BHND/4/256), 256, 0, stream>>>(Opart, lpart, out);
  } else {
    attn_kernel<16, false><<<dim3(BB*HH*(NN/64), 1), 256, 0, stream>>>(
        Qb, Kb, Vt, adj, mask, shifts, widths, slwp, out, Opart, lpart);
  }
}